// Round 10
// baseline (1887.386 us; speedup 1.0000x reference)
//
#include <hip/hip_runtime.h>

// _GSPostProcessor: out = D^{-1/2} (topk20(relu(A) + dope*1e-4)*relu(A) + I) D^{-1/2}
// B=16, N=2048, K=20.
// R10: persistent producer-consumer pipeline via REGULAR launch (R9's cooperative
// launch failed graph capture). Overlaps the read phase (~3.3 TB/s cap) with the
// write phase (~7 TB/s):
//   all blocks: drain produce queue (R7-proven pass1, 8-row chunks, release done[batch])
//   then: drain consume queue (R7-proven register scatter, acquire done[batch])
//   consume-only blocks (384..511) skip straight to consuming.
// Deadlock-free without co-residency guarantees: consume starts only after the
// produce queue is fully claimed, and every claimant finishes its chunks first.
// ctrl words (wq, cq, done[16]) live in d_ws, zeroed by hipMemsetAsync each call.

static constexpr int N      = 2048;
static constexpr int KSEL   = 20;
static constexpr int NR     = 16 * 2048;  // B*N rows
static constexpr int CHROWS = 8;          // rows per chunk (2048 % 8 == 0: no batch straddle)
static constexpr int NCHUNK = NR / CHROWS;
static constexpr int GRID   = 512;        // 2 blocks/CU -> co-resident even at 256 VGPR
static constexpr int PBLK   = 384;        // blocks that produce first

typedef unsigned int uint2v __attribute__((ext_vector_type(2)));
typedef float f32x4 __attribute__((ext_vector_type(4)));

#if __has_builtin(__builtin_nontemporal_load)
#define NT_LOAD(p) __builtin_nontemporal_load(p)
#else
#define NT_LOAD(p) (*(p))
#endif
#if __has_builtin(__builtin_nontemporal_store)
#define NT_STORE(v, p) __builtin_nontemporal_store((v), (p))
#else
#define NT_STORE(v, p) (*(p) = (v))
#endif

// ---------------- cross-lane primitives ----------------
#if __has_builtin(__builtin_amdgcn_mov_dpp)
#define XD(v, ctrl) ((unsigned)__builtin_amdgcn_mov_dpp((int)(v), (ctrl), 0xF, 0xF, false))
#else
#define XD(v, ctrl) ((unsigned)__shfl_xor((int)(v), ((ctrl) == 0xB1 ? 1 : 2)))
#endif
#if __has_builtin(__builtin_amdgcn_ds_swizzle)
#define XS(v, imm) ((unsigned)__builtin_amdgcn_ds_swizzle((int)(v), (imm)))
#else
#define XS(v, imm) ((unsigned)__shfl_xor((int)(v), (((imm) >> 10) & 0x1F)))
#endif

__device__ __forceinline__ unsigned read_lane_u32(unsigned v, int srclane) {
#if __has_builtin(__builtin_amdgcn_readlane)
  return (unsigned)__builtin_amdgcn_readlane((int)v, srclane);
#else
  return (unsigned)__shfl((int)v, srclane, 64);
#endif
}

// compare-exchange: {A,B} = {self, partner} (order irrelevant); keep max iff km.
__device__ __forceinline__ void cex(unsigned& hi, unsigned& lo,
                                    unsigned Ahi, unsigned Alo,
                                    unsigned Bhi, unsigned Blo, bool km) {
  unsigned long long Av = ((unsigned long long)Ahi << 32) | Alo;
  unsigned long long Bv = ((unsigned long long)Bhi << 32) | Blo;
  bool sel = (km == (Av > Bv));
  hi = sel ? Ahi : Bhi;
  lo = sel ? Alo : Blo;
}

#define KM(K2, J) ((((lane & (J)) == 0)) != (((lane & (K2)) != 0)))
#define EX1(K2)  cex(hi, lo, hi, lo, XD(hi, 0xB1), XD(lo, 0xB1), KM(K2, 1))
#define EX2(K2)  cex(hi, lo, hi, lo, XD(hi, 0x4E), XD(lo, 0x4E), KM(K2, 2))
#define EX4(K2)  cex(hi, lo, hi, lo, XS(hi, 0x101F), XS(lo, 0x101F), KM(K2, 4))
#define EX8(K2)  cex(hi, lo, hi, lo, XS(hi, 0x201F), XS(lo, 0x201F), KM(K2, 8))
#if __has_builtin(__builtin_amdgcn_permlane16_swap)
#define EX16(K2) { uint2v r_ = __builtin_amdgcn_permlane16_swap(hi, hi, false, false); \
                   uint2v s_ = __builtin_amdgcn_permlane16_swap(lo, lo, false, false); \
                   cex(hi, lo, (unsigned)r_[0], (unsigned)s_[0], (unsigned)r_[1], (unsigned)s_[1], KM(K2, 16)); }
#else
#define EX16(K2) cex(hi, lo, hi, lo, (unsigned)__shfl_xor((int)hi, 16), (unsigned)__shfl_xor((int)lo, 16), KM(K2, 16))
#endif
#if __has_builtin(__builtin_amdgcn_permlane32_swap)
#define EX32(K2) { uint2v r_ = __builtin_amdgcn_permlane32_swap(hi, hi, false, false); \
                   uint2v s_ = __builtin_amdgcn_permlane32_swap(lo, lo, false, false); \
                   cex(hi, lo, (unsigned)r_[0], (unsigned)s_[0], (unsigned)r_[1], (unsigned)s_[1], KM(K2, 32)); }
#else
#define EX32(K2) cex(hi, lo, hi, lo, (unsigned)__shfl_xor((int)hi, 32), (unsigned)__shfl_xor((int)lo, 32), KM(K2, 32))
#endif

#define SORT64() do {                                     \
    EX1(2);                                               \
    EX2(4);  EX1(4);                                      \
    EX4(8);  EX2(8);  EX1(8);                             \
    EX8(16); EX4(16); EX2(16); EX1(16);                   \
    EX16(32); EX8(32); EX4(32); EX2(32); EX1(32);         \
    EX32(64); EX16(64); EX8(64); EX4(64); EX2(64); EX1(64); \
  } while (0)

// ---------------- exact (R1-proven) doped path ----------------
__device__ __forceinline__ void ins4(float vc, int jc,
                                     float& t0, float& t1, float& t2, float& t3,
                                     int& j0, int& j1, int& j2, int& j3) {
  bool b0 = vc > t0;
  float d0 = b0 ? t0 : vc; int e0 = b0 ? j0 : jc;
  t0 = b0 ? vc : t0;       j0 = b0 ? jc : j0;
  bool b1 = d0 > t1;
  float d1 = b1 ? t1 : d0; int e1 = b1 ? j1 : e0;
  t1 = b1 ? d0 : t1;       j1 = b1 ? e0 : j1;
  bool b2 = d1 > t2;
  float d2 = b2 ? t2 : d1; int e2 = b2 ? j2 : e1;
  t2 = b2 ? d1 : t2;       j2 = b2 ? e1 : j2;
  bool b3 = d2 > t3;
  t3 = b3 ? d2 : t3;       j3 = b3 ? e2 : j3;
}

__device__ __forceinline__ int wave_topk_exact(const float* __restrict__ Arow,
                                               const float* __restrict__ Drow,
                                               int lane) {
  float v[32];
  const float4* A4 = reinterpret_cast<const float4*>(Arow);
  const float4* D4 = reinterpret_cast<const float4*>(Drow);
#pragma unroll
  for (int c4 = 0; c4 < 8; ++c4) {
    float4 a = A4[c4 * 64 + lane];
    float4 d = D4[c4 * 64 + lane];
    v[c4 * 4 + 0] = __fadd_rn(fmaxf(a.x, 0.0f), __fmul_rn(d.x, 1e-4f));
    v[c4 * 4 + 1] = __fadd_rn(fmaxf(a.y, 0.0f), __fmul_rn(d.y, 1e-4f));
    v[c4 * 4 + 2] = __fadd_rn(fmaxf(a.z, 0.0f), __fmul_rn(d.z, 1e-4f));
    v[c4 * 4 + 3] = __fadd_rn(fmaxf(a.w, 0.0f), __fmul_rn(d.w, 1e-4f));
  }
  float t0 = -1.f, t1 = -1.f, t2 = -1.f, t3 = -1.f;
  int   j0 = 0,    j1 = 0,    j2 = 0,    j3 = 0;
#pragma unroll
  for (int c = 0; c < 32; ++c) {
    int jc = ((c >> 2) << 8) | (lane << 2) | (c & 3);
    ins4(v[c], jc, t0, t1, t2, t3, j0, j1, j2, j3);
  }
  unsigned consumed = 0;
  int jmine = 0;
#pragma unroll 1
  for (int it = 0; it < KSEL; ++it) {
    if (__any(t0 < 0.0f)) {
      if (t0 < 0.0f) {
        t0 = t1 = t2 = t3 = -1.f; j0 = j1 = j2 = j3 = 0;
#pragma unroll
        for (int c = 0; c < 32; ++c) {
          float vc = ((consumed >> c) & 1u) ? -1.0f : v[c];
          int jc = ((c >> 2) << 8) | (lane << 2) | (c & 3);
          ins4(vc, jc, t0, t1, t2, t3, j0, j1, j2, j3);
        }
      }
    }
    float m = t0;
#pragma unroll
    for (int off = 32; off; off >>= 1) m = fmaxf(m, __shfl_xor(m, off));
    int cj = (t0 == m) ? j0 : 0x7fffffff;
#pragma unroll
    for (int off = 32; off; off >>= 1) cj = min(cj, __shfl_xor(cj, off));
    if (lane == it) jmine = cj;
    if (((cj >> 2) & 63) == lane) {
      int c = ((cj >> 8) << 2) | (cj & 3);
      consumed |= (1u << c);
      t0 = t1; j0 = j1; t1 = t2; j1 = j2; t2 = t3; j2 = j3; t3 = -1.f; j3 = 0;
    }
  }
  return jmine;
}

// ---------------- R7-proven pass1 for one row (wave-level) ----------------
__device__ __forceinline__ void produce_row(const float* __restrict__ A,
                                            const float* __restrict__ D,
                                            float* __restrict__ wval,
                                            int* __restrict__ widx,
                                            float* __restrict__ wdinv,
                                            int r, int lane, int w,
                                            unsigned long long (*cand)[64],
                                            unsigned* scnt) {
  const float T = 2.05f;
  size_t base = (size_t)r * N;
  const f32x4* A4 = reinterpret_cast<const f32x4*>(A + base);

  f32x4 a0 = NT_LOAD(A4 + lane);       f32x4 a1 = NT_LOAD(A4 + 64 + lane);
  f32x4 a2 = NT_LOAD(A4 + 128 + lane); f32x4 a3 = NT_LOAD(A4 + 192 + lane);
  f32x4 a4 = NT_LOAD(A4 + 256 + lane); f32x4 a5 = NT_LOAD(A4 + 320 + lane);
  f32x4 a6 = NT_LOAD(A4 + 384 + lane); f32x4 a7 = NT_LOAD(A4 + 448 + lane);

  cand[w][lane] = 0ull;        // padding sorts to the bottom (real keys > T > 0)
  if (lane == 0) scnt[w] = 0u;

#define PUSH1(AV, J) do {                                                      \
    float k_ = fmaxf((AV), 0.0f);                                              \
    if (k_ > T) {                                                              \
      unsigned p_ = atomicAdd(&scnt[w], 1u);                                   \
      if (p_ < 64u)                                                            \
        cand[w][p_] = ((unsigned long long)__float_as_uint(k_) << 32) |        \
                      (unsigned)(2047 - (J));                                  \
    }                                                                          \
  } while (0)
#define PUSH4(AA, C4) do {                                                     \
    int jb_ = ((C4) << 8) | (lane << 2);                                       \
    PUSH1(AA.x, jb_ + 0);                                                      \
    PUSH1(AA.y, jb_ + 1);                                                      \
    PUSH1(AA.z, jb_ + 2);                                                      \
    PUSH1(AA.w, jb_ + 3);                                                      \
  } while (0)

  PUSH4(a0, 0); PUSH4(a1, 1); PUSH4(a2, 2); PUSH4(a3, 3);
  PUSH4(a4, 4); PUSH4(a5, 5); PUSH4(a6, 6); PUSH4(a7, 7);
#undef PUSH4
#undef PUSH1

  // wave-private LDS; drain DS pipe before cross-lane reads
  __asm__ __volatile__("s_waitcnt lgkmcnt(0)" ::: "memory");
  unsigned cnt = scnt[w];
  unsigned long long kv = cand[w][lane];
  unsigned hi = (unsigned)(kv >> 32), lo = (unsigned)kv;
  SORT64();

  // Set-exactness guard: doped keys shift by at most +1e-4 (exact fp32 bound).
  float a19 = __uint_as_float(read_lane_u32(hi, 19));
  float a20 = __uint_as_float(read_lane_u32(hi, 20));
  bool decided = (a19 > __fadd_rn(a20, 1e-4f)) && (a19 > __fadd_rn(T, 1e-4f));
  bool bad = (cnt < (unsigned)KSEL) || (cnt > 64u) || !decided;  // wave-uniform

  int jsel = 2047 - (int)lo;
  float val = (lane < KSEL) ? __uint_as_float(hi) : 0.0f;  // sorted key IS relu(a)

  if (bad) {                    // ~0.3% of waves: exact doped redo
    int jm = wave_topk_exact(A + base, D + base, lane);
    jsel = jm;
    val = (lane < KSEL) ? fmaxf(A[base + jm], 0.0f) : 0.0f;
  }

  float s = val;
#pragma unroll
  for (int off = 32; off; off >>= 1) s += __shfl_xor(s, off);
  float dinv = (float)(1.0 / sqrt(1.0 + (double)s));       // row sum >= 1, never inf

  if (lane < KSEL) {
    wval[r * KSEL + lane] = val;
    widx[r * KSEL + lane] = jsel;
  }
  if (lane == 0) wdinv[r] = dinv;
}

// ---------------- R7-proven register-compose scatter for one row ----------------
__device__ __forceinline__ void scatter_row(const float* __restrict__ wval,
                                            const int* __restrict__ widx,
                                            const float* __restrict__ wdinv,
                                            float* __restrict__ out,
                                            int r, int tid) {
  int i = r & (N - 1);
  int bb = r & ~(N - 1);                 // batch row-base
  float di = wdinv[r];

  float v0 = 0.f, v1 = 0.f, v2 = 0.f, v3 = 0.f,
        v4 = 0.f, v5 = 0.f, v6 = 0.f, v7 = 0.f;
  if ((i & 255) == tid) {
    float dd = di * di;
    switch (i >> 8) {
      case 0: v0 = dd; break; case 1: v1 = dd; break;
      case 2: v2 = dd; break; case 3: v3 = dd; break;
      case 4: v4 = dd; break; case 5: v5 = dd; break;
      case 6: v6 = dd; break; case 7: v7 = dd; break;
    }
  }
#pragma unroll
  for (int t = 0; t < KSEL; ++t) {
    int j = widx[r * KSEL + t];          // uniform -> scalar load
    if ((j & 255) == tid) {              // <=20 of 256 threads hit
      float c = di * wval[r * KSEL + t] * wdinv[bb + j];
      switch (j >> 8) {
        case 0: v0 += c; break; case 1: v1 += c; break;
        case 2: v2 += c; break; case 3: v3 += c; break;
        case 4: v4 += c; break; case 5: v5 += c; break;
        case 6: v6 += c; break; case 7: v7 += c; break;
      }
    }
  }
  float* o = out + (size_t)r * N;
  NT_STORE(v0, o + tid);         NT_STORE(v1, o + 256 + tid);
  NT_STORE(v2, o + 512 + tid);   NT_STORE(v3, o + 768 + tid);
  NT_STORE(v4, o + 1024 + tid);  NT_STORE(v5, o + 1280 + tid);
  NT_STORE(v6, o + 1536 + tid);  NT_STORE(v7, o + 1792 + tid);
}

// ---------------- persistent pipeline kernel (regular launch) ----------------
// ctrl[0]=produce queue, ctrl[1]=consume queue, ctrl[16+b]=rows done in batch b
__global__ void __launch_bounds__(256)
pipeline(const float* __restrict__ A, const float* __restrict__ D,
         float* __restrict__ wval, int* __restrict__ widx,
         float* __restrict__ wdinv, float* __restrict__ out,
         unsigned* __restrict__ ctrl) {
  __shared__ unsigned long long cand[4][64];
  __shared__ unsigned scnt[4];
  __shared__ unsigned sh_chunk;
  const int tid = threadIdx.x, lane = tid & 63, w = tid >> 6;

  if ((int)blockIdx.x < PBLK) {
    for (;;) {
      __syncthreads();
      if (tid == 0) sh_chunk = atomicAdd(&ctrl[0], 1u);
      __syncthreads();
      unsigned chunk = sh_chunk;
      if (chunk >= (unsigned)NCHUNK) break;
      int r0 = (int)chunk * CHROWS + w * 2;   // wave does 2 rows
      produce_row(A, D, wval, widx, wdinv, r0,     lane, w, cand, scnt);
      produce_row(A, D, wval, widx, wdinv, r0 + 1, lane, w, cand, scnt);
      // publish: ALL lanes fence (orders every lane's stores), then lane 0 counts
      __threadfence();
      if (lane == 0)
        __hip_atomic_fetch_add(&ctrl[16 + (((int)chunk * CHROWS) >> 11)], 2u,
                               __ATOMIC_RELEASE, __HIP_MEMORY_SCOPE_AGENT);
    }
  }

  // consume (blocks >= PBLK from the start; producers after the queue drains)
  for (;;) {
    __syncthreads();
    if (tid == 0) sh_chunk = atomicAdd(&ctrl[1], 1u);
    __syncthreads();
    unsigned chunk = sh_chunk;
    if (chunk >= (unsigned)NCHUNK) break;
    int b = ((int)chunk * CHROWS) >> 11;
    if (tid == 0) {
      // cheap relaxed polling; one acquire once the batch is complete
      while (__hip_atomic_load(&ctrl[16 + b], __ATOMIC_RELAXED,
                               __HIP_MEMORY_SCOPE_AGENT) < 2048u) {
#if __has_builtin(__builtin_amdgcn_s_sleep)
        __builtin_amdgcn_s_sleep(16);
#endif
      }
      (void)__hip_atomic_load(&ctrl[16 + b], __ATOMIC_ACQUIRE,
                              __HIP_MEMORY_SCOPE_AGENT);
    }
    __syncthreads();
#pragma unroll 1
    for (int k = 0; k < CHROWS; ++k)
      scatter_row(wval, widx, wdinv, out, (int)chunk * CHROWS + k, tid);
  }
}

// ---------------- fallback (tiny ws): exact fused path, R1-proven ----------------
__global__ void __launch_bounds__(256)
topk_exact_pass1(const float* __restrict__ A, const float* __restrict__ D,
                 float* __restrict__ wdinv) {
  int lane = threadIdx.x & 63;
  int r = blockIdx.x * 4 + (threadIdx.x >> 6);
  size_t base = (size_t)r * N;
  int jm = wave_topk_exact(A + base, D + base, lane);
  float val = 0.0f;
  if (lane < KSEL) val = fmaxf(A[base + jm], 0.0f);
  float s = (lane < KSEL) ? val : 0.0f;
#pragma unroll
  for (int off = 32; off; off >>= 1) s += __shfl_xor(s, off);
  float dinv = (float)(1.0 / sqrt(1.0 + (double)s));
  if (lane == 0) wdinv[r] = dinv;
}

__global__ void __launch_bounds__(256)
fallback_pass2(const float* __restrict__ A, const float* __restrict__ D,
               const float* __restrict__ wdinv, float* __restrict__ out) {
  __shared__ float rows[4][N];
  int lane = threadIdx.x & 63;
  int w = threadIdx.x >> 6;
  int r = blockIdx.x * 4 + w;
  size_t base = (size_t)r * N;
  int i = r & (N - 1);
  int jm = wave_topk_exact(A + base, D + base, lane);
  float val = 0.0f;
  if (lane < KSEL) val = fmaxf(A[base + jm], 0.0f);
  float s = (lane < KSEL) ? val : 0.0f;
#pragma unroll
  for (int off = 32; off; off >>= 1) s += __shfl_xor(s, off);
  float di = (float)(1.0 / sqrt(1.0 + (double)s));
  float4* rv = reinterpret_cast<float4*>(rows[w]);
  float4 z = make_float4(0.f, 0.f, 0.f, 0.f);
#pragma unroll
  for (int q = 0; q < 8; ++q) rv[q * 64 + lane] = z;
  __syncthreads();
  if (lane < KSEL) {
    float dj = wdinv[(r & ~(N - 1)) + jm];
    atomicAdd(&rows[w][jm], di * val * dj);
  } else if (lane == KSEL) {
    atomicAdd(&rows[w][i], di * di);
  }
  __syncthreads();
  float4* o4 = reinterpret_cast<float4*>(out + base);
#pragma unroll
  for (int q = 0; q < 8; ++q) o4[q * 64 + lane] = rv[q * 64 + lane];
}

extern "C" void kernel_launch(void* const* d_in, const int* in_sizes, int n_in,
                              void* d_out, int out_size, void* d_ws, size_t ws_size,
                              hipStream_t stream) {
  const float* A = (const float*)d_in[0];
  const float* D = (const float*)d_in[1];
  float* out = (float*)d_out;
  char* ws = (char*)d_ws;
  size_t off_val  = 0;
  size_t off_idx  = off_val + (size_t)NR * KSEL * sizeof(float);
  size_t off_dinv = off_idx + (size_t)NR * KSEL * sizeof(int);
  size_t off_ctrl = off_dinv + (size_t)NR * sizeof(float);
  off_ctrl = (off_ctrl + 255) & ~(size_t)255;
  size_t total    = off_ctrl + 128;
  if (ws_size >= total) {
    float*    wval  = (float*)(ws + off_val);
    int*      widx  = (int*)(ws + off_idx);
    float*    wdinv = (float*)(ws + off_dinv);
    unsigned* ctrl  = (unsigned*)(ws + off_ctrl);
    hipMemsetAsync(ctrl, 0, 128, stream);
    pipeline<<<GRID, 256, 0, stream>>>(A, D, wval, widx, wdinv, out, ctrl);
  } else {
    float* wdinv = (float*)ws;
    topk_exact_pass1<<<NR / 4, 256, 0, stream>>>(A, D, wdinv);
    fallback_pass2<<<NR / 4, 256, 0, stream>>>(A, D, wdinv, out);
  }
}

// Round 11
// 178.347 us; speedup vs baseline: 10.5827x; 10.5827x over previous
//
#include <hip/hip_runtime.h>

// _GSPostProcessor: out = D^{-1/2} (topk20(relu(A) + dope*1e-4)*relu(A) + I) D^{-1/2}
// B=16, N=2048, K=20.
// R11: read/write overlap WITHOUT atomics, using kernel-launch boundaries as the
// producer->consumer fence (each dispatch acquires at start / releases at end).
// 4 super-batches (SB = 4 batches = 8192 rows), 5 plain launches:
//   L0 : produce SB0
//   L1-3: 2048 blocks produce SB(k)  ||  1024 blocks scatter SB(k-1)  (roles
//         interleaved 2:1 in dispatch order; no inter-block communication)
//   L4 : scatter SB3
// produce_row / scatter_row are byte-identical to the R7/R8-proven versions.

static constexpr int N      = 2048;
static constexpr int KSEL   = 20;
static constexpr int NR     = 16 * 2048;  // B*N rows
static constexpr int SBROWS = 8192;       // 4 batches per super-batch

typedef unsigned int uint2v __attribute__((ext_vector_type(2)));
typedef float f32x4 __attribute__((ext_vector_type(4)));

#if __has_builtin(__builtin_nontemporal_load)
#define NT_LOAD(p) __builtin_nontemporal_load(p)
#else
#define NT_LOAD(p) (*(p))
#endif
#if __has_builtin(__builtin_nontemporal_store)
#define NT_STORE(v, p) __builtin_nontemporal_store((v), (p))
#else
#define NT_STORE(v, p) (*(p) = (v))
#endif

// ---------------- cross-lane primitives ----------------
#if __has_builtin(__builtin_amdgcn_mov_dpp)
#define XD(v, ctrl) ((unsigned)__builtin_amdgcn_mov_dpp((int)(v), (ctrl), 0xF, 0xF, false))
#else
#define XD(v, ctrl) ((unsigned)__shfl_xor((int)(v), ((ctrl) == 0xB1 ? 1 : 2)))
#endif
#if __has_builtin(__builtin_amdgcn_ds_swizzle)
#define XS(v, imm) ((unsigned)__builtin_amdgcn_ds_swizzle((int)(v), (imm)))
#else
#define XS(v, imm) ((unsigned)__shfl_xor((int)(v), (((imm) >> 10) & 0x1F)))
#endif

__device__ __forceinline__ unsigned read_lane_u32(unsigned v, int srclane) {
#if __has_builtin(__builtin_amdgcn_readlane)
  return (unsigned)__builtin_amdgcn_readlane((int)v, srclane);
#else
  return (unsigned)__shfl((int)v, srclane, 64);
#endif
}

// compare-exchange: {A,B} = {self, partner} (order irrelevant); keep max iff km.
__device__ __forceinline__ void cex(unsigned& hi, unsigned& lo,
                                    unsigned Ahi, unsigned Alo,
                                    unsigned Bhi, unsigned Blo, bool km) {
  unsigned long long Av = ((unsigned long long)Ahi << 32) | Alo;
  unsigned long long Bv = ((unsigned long long)Bhi << 32) | Blo;
  bool sel = (km == (Av > Bv));
  hi = sel ? Ahi : Bhi;
  lo = sel ? Alo : Blo;
}

#define KM(K2, J) ((((lane & (J)) == 0)) != (((lane & (K2)) != 0)))
#define EX1(K2)  cex(hi, lo, hi, lo, XD(hi, 0xB1), XD(lo, 0xB1), KM(K2, 1))
#define EX2(K2)  cex(hi, lo, hi, lo, XD(hi, 0x4E), XD(lo, 0x4E), KM(K2, 2))
#define EX4(K2)  cex(hi, lo, hi, lo, XS(hi, 0x101F), XS(lo, 0x101F), KM(K2, 4))
#define EX8(K2)  cex(hi, lo, hi, lo, XS(hi, 0x201F), XS(lo, 0x201F), KM(K2, 8))
#if __has_builtin(__builtin_amdgcn_permlane16_swap)
#define EX16(K2) { uint2v r_ = __builtin_amdgcn_permlane16_swap(hi, hi, false, false); \
                   uint2v s_ = __builtin_amdgcn_permlane16_swap(lo, lo, false, false); \
                   cex(hi, lo, (unsigned)r_[0], (unsigned)s_[0], (unsigned)r_[1], (unsigned)s_[1], KM(K2, 16)); }
#else
#define EX16(K2) cex(hi, lo, hi, lo, (unsigned)__shfl_xor((int)hi, 16), (unsigned)__shfl_xor((int)lo, 16), KM(K2, 16))
#endif
#if __has_builtin(__builtin_amdgcn_permlane32_swap)
#define EX32(K2) { uint2v r_ = __builtin_amdgcn_permlane32_swap(hi, hi, false, false); \
                   uint2v s_ = __builtin_amdgcn_permlane32_swap(lo, lo, false, false); \
                   cex(hi, lo, (unsigned)r_[0], (unsigned)s_[0], (unsigned)r_[1], (unsigned)s_[1], KM(K2, 32)); }
#else
#define EX32(K2) cex(hi, lo, hi, lo, (unsigned)__shfl_xor((int)hi, 32), (unsigned)__shfl_xor((int)lo, 32), KM(K2, 32))
#endif

#define SORT64() do {                                     \
    EX1(2);                                               \
    EX2(4);  EX1(4);                                      \
    EX4(8);  EX2(8);  EX1(8);                             \
    EX8(16); EX4(16); EX2(16); EX1(16);                   \
    EX16(32); EX8(32); EX4(32); EX2(32); EX1(32);         \
    EX32(64); EX16(64); EX8(64); EX4(64); EX2(64); EX1(64); \
  } while (0)

// ---------------- exact (R1-proven) doped path ----------------
__device__ __forceinline__ void ins4(float vc, int jc,
                                     float& t0, float& t1, float& t2, float& t3,
                                     int& j0, int& j1, int& j2, int& j3) {
  bool b0 = vc > t0;
  float d0 = b0 ? t0 : vc; int e0 = b0 ? j0 : jc;
  t0 = b0 ? vc : t0;       j0 = b0 ? jc : j0;
  bool b1 = d0 > t1;
  float d1 = b1 ? t1 : d0; int e1 = b1 ? j1 : e0;
  t1 = b1 ? d0 : t1;       j1 = b1 ? e0 : j1;
  bool b2 = d1 > t2;
  float d2 = b2 ? t2 : d1; int e2 = b2 ? j2 : e1;
  t2 = b2 ? d1 : t2;       j2 = b2 ? e1 : j2;
  bool b3 = d2 > t3;
  t3 = b3 ? d2 : t3;       j3 = b3 ? e2 : j3;
}

__device__ __forceinline__ int wave_topk_exact(const float* __restrict__ Arow,
                                               const float* __restrict__ Drow,
                                               int lane) {
  float v[32];
  const float4* A4 = reinterpret_cast<const float4*>(Arow);
  const float4* D4 = reinterpret_cast<const float4*>(Drow);
#pragma unroll
  for (int c4 = 0; c4 < 8; ++c4) {
    float4 a = A4[c4 * 64 + lane];
    float4 d = D4[c4 * 64 + lane];
    v[c4 * 4 + 0] = __fadd_rn(fmaxf(a.x, 0.0f), __fmul_rn(d.x, 1e-4f));
    v[c4 * 4 + 1] = __fadd_rn(fmaxf(a.y, 0.0f), __fmul_rn(d.y, 1e-4f));
    v[c4 * 4 + 2] = __fadd_rn(fmaxf(a.z, 0.0f), __fmul_rn(d.z, 1e-4f));
    v[c4 * 4 + 3] = __fadd_rn(fmaxf(a.w, 0.0f), __fmul_rn(d.w, 1e-4f));
  }
  float t0 = -1.f, t1 = -1.f, t2 = -1.f, t3 = -1.f;
  int   j0 = 0,    j1 = 0,    j2 = 0,    j3 = 0;
#pragma unroll
  for (int c = 0; c < 32; ++c) {
    int jc = ((c >> 2) << 8) | (lane << 2) | (c & 3);
    ins4(v[c], jc, t0, t1, t2, t3, j0, j1, j2, j3);
  }
  unsigned consumed = 0;
  int jmine = 0;
#pragma unroll 1
  for (int it = 0; it < KSEL; ++it) {
    if (__any(t0 < 0.0f)) {
      if (t0 < 0.0f) {
        t0 = t1 = t2 = t3 = -1.f; j0 = j1 = j2 = j3 = 0;
#pragma unroll
        for (int c = 0; c < 32; ++c) {
          float vc = ((consumed >> c) & 1u) ? -1.0f : v[c];
          int jc = ((c >> 2) << 8) | (lane << 2) | (c & 3);
          ins4(vc, jc, t0, t1, t2, t3, j0, j1, j2, j3);
        }
      }
    }
    float m = t0;
#pragma unroll
    for (int off = 32; off; off >>= 1) m = fmaxf(m, __shfl_xor(m, off));
    int cj = (t0 == m) ? j0 : 0x7fffffff;
#pragma unroll
    for (int off = 32; off; off >>= 1) cj = min(cj, __shfl_xor(cj, off));
    if (lane == it) jmine = cj;
    if (((cj >> 2) & 63) == lane) {
      int c = ((cj >> 8) << 2) | (cj & 3);
      consumed |= (1u << c);
      t0 = t1; j0 = j1; t1 = t2; j1 = j2; t2 = t3; j2 = j3; t3 = -1.f; j3 = 0;
    }
  }
  return jmine;
}

// ---------------- R7-proven pass1 for one row (wave-level) ----------------
__device__ __forceinline__ void produce_row(const float* __restrict__ A,
                                            const float* __restrict__ D,
                                            float* __restrict__ wval,
                                            int* __restrict__ widx,
                                            float* __restrict__ wdinv,
                                            int r, int lane, int w,
                                            unsigned long long (*cand)[64],
                                            unsigned* scnt) {
  const float T = 2.05f;
  size_t base = (size_t)r * N;
  const f32x4* A4 = reinterpret_cast<const f32x4*>(A + base);

  f32x4 a0 = NT_LOAD(A4 + lane);       f32x4 a1 = NT_LOAD(A4 + 64 + lane);
  f32x4 a2 = NT_LOAD(A4 + 128 + lane); f32x4 a3 = NT_LOAD(A4 + 192 + lane);
  f32x4 a4 = NT_LOAD(A4 + 256 + lane); f32x4 a5 = NT_LOAD(A4 + 320 + lane);
  f32x4 a6 = NT_LOAD(A4 + 384 + lane); f32x4 a7 = NT_LOAD(A4 + 448 + lane);

  cand[w][lane] = 0ull;        // padding sorts to the bottom (real keys > T > 0)
  if (lane == 0) scnt[w] = 0u;

#define PUSH1(AV, J) do {                                                      \
    float k_ = fmaxf((AV), 0.0f);                                              \
    if (k_ > T) {                                                              \
      unsigned p_ = atomicAdd(&scnt[w], 1u);                                   \
      if (p_ < 64u)                                                            \
        cand[w][p_] = ((unsigned long long)__float_as_uint(k_) << 32) |        \
                      (unsigned)(2047 - (J));                                  \
    }                                                                          \
  } while (0)
#define PUSH4(AA, C4) do {                                                     \
    int jb_ = ((C4) << 8) | (lane << 2);                                       \
    PUSH1(AA.x, jb_ + 0);                                                      \
    PUSH1(AA.y, jb_ + 1);                                                      \
    PUSH1(AA.z, jb_ + 2);                                                      \
    PUSH1(AA.w, jb_ + 3);                                                      \
  } while (0)

  PUSH4(a0, 0); PUSH4(a1, 1); PUSH4(a2, 2); PUSH4(a3, 3);
  PUSH4(a4, 4); PUSH4(a5, 5); PUSH4(a6, 6); PUSH4(a7, 7);
#undef PUSH4
#undef PUSH1

  // wave-private LDS; drain DS pipe before cross-lane reads
  __asm__ __volatile__("s_waitcnt lgkmcnt(0)" ::: "memory");
  unsigned cnt = scnt[w];
  unsigned long long kv = cand[w][lane];
  unsigned hi = (unsigned)(kv >> 32), lo = (unsigned)kv;
  SORT64();

  // Set-exactness guard: doped keys shift by at most +1e-4 (exact fp32 bound).
  float a19 = __uint_as_float(read_lane_u32(hi, 19));
  float a20 = __uint_as_float(read_lane_u32(hi, 20));
  bool decided = (a19 > __fadd_rn(a20, 1e-4f)) && (a19 > __fadd_rn(T, 1e-4f));
  bool bad = (cnt < (unsigned)KSEL) || (cnt > 64u) || !decided;  // wave-uniform

  int jsel = 2047 - (int)lo;
  float val = (lane < KSEL) ? __uint_as_float(hi) : 0.0f;  // sorted key IS relu(a)

  if (bad) {                    // ~0.3% of waves: exact doped redo
    int jm = wave_topk_exact(A + base, D + base, lane);
    jsel = jm;
    val = (lane < KSEL) ? fmaxf(A[base + jm], 0.0f) : 0.0f;
  }

  float s = val;
#pragma unroll
  for (int off = 32; off; off >>= 1) s += __shfl_xor(s, off);
  float dinv = (float)(1.0 / sqrt(1.0 + (double)s));       // row sum >= 1, never inf

  if (lane < KSEL) {
    wval[r * KSEL + lane] = val;
    widx[r * KSEL + lane] = jsel;
  }
  if (lane == 0) wdinv[r] = dinv;
}

// ---------------- R7-proven register-compose scatter for one row ----------------
__device__ __forceinline__ void scatter_row(const float* __restrict__ wval,
                                            const int* __restrict__ widx,
                                            const float* __restrict__ wdinv,
                                            float* __restrict__ out,
                                            int r, int tid) {
  int i = r & (N - 1);
  int bb = r & ~(N - 1);                 // batch row-base
  float di = wdinv[r];

  float v0 = 0.f, v1 = 0.f, v2 = 0.f, v3 = 0.f,
        v4 = 0.f, v5 = 0.f, v6 = 0.f, v7 = 0.f;
  if ((i & 255) == tid) {
    float dd = di * di;
    switch (i >> 8) {
      case 0: v0 = dd; break; case 1: v1 = dd; break;
      case 2: v2 = dd; break; case 3: v3 = dd; break;
      case 4: v4 = dd; break; case 5: v5 = dd; break;
      case 6: v6 = dd; break; case 7: v7 = dd; break;
    }
  }
#pragma unroll
  for (int t = 0; t < KSEL; ++t) {
    int j = widx[r * KSEL + t];          // uniform -> scalar load
    if ((j & 255) == tid) {              // <=20 of 256 threads hit
      float c = di * wval[r * KSEL + t] * wdinv[bb + j];
      switch (j >> 8) {
        case 0: v0 += c; break; case 1: v1 += c; break;
        case 2: v2 += c; break; case 3: v3 += c; break;
        case 4: v4 += c; break; case 5: v5 += c; break;
        case 6: v6 += c; break; case 7: v7 += c; break;
      }
    }
  }
  float* o = out + (size_t)r * N;
  NT_STORE(v0, o + tid);         NT_STORE(v1, o + 256 + tid);
  NT_STORE(v2, o + 512 + tid);   NT_STORE(v3, o + 768 + tid);
  NT_STORE(v4, o + 1024 + tid);  NT_STORE(v5, o + 1280 + tid);
  NT_STORE(v6, o + 1536 + tid);  NT_STORE(v7, o + 1792 + tid);
}

// ---------------- mixed kernel: some blocks produce SB(k), some scatter SB(k-1) --------
// np4 producer blocks (4 rows each), ns8 scatter blocks (8 rows each).
// When both roles present (np4 == 2*ns8), roles interleave 2:1 in dispatch order.
__global__ void __launch_bounds__(256)
mixed(const float* __restrict__ A, const float* __restrict__ D,
      float* __restrict__ wval, int* __restrict__ widx,
      float* __restrict__ wdinv, float* __restrict__ out,
      int prow0, int np4, int srow0, int ns8) {
  __shared__ unsigned long long cand[4][64];
  __shared__ unsigned scnt[4];
  const int tid = threadIdx.x, lane = tid & 63, w = tid >> 6;
  int g = blockIdx.x;
  bool prod;
  int ri;
  if (ns8 == 0)       { prod = true;  ri = g; }
  else if (np4 == 0)  { prod = false; ri = g; }
  else {  // interleave 2 producers : 1 scatterer
    if ((g % 3) == 2) { prod = false; ri = g / 3; }
    else              { prod = true;  ri = (g / 3) * 2 + (g % 3); }
  }
  if (prod) {
    int r = prow0 + ri * 4 + w;          // one row per wave
    produce_row(A, D, wval, widx, wdinv, r, lane, w, cand, scnt);
  } else {
#pragma unroll 1
    for (int k = 0; k < 8; ++k)
      scatter_row(wval, widx, wdinv, out, srow0 + ri * 8 + k, tid);
  }
}

// ---------------- fallback (tiny ws): exact fused path, R1-proven ----------------
__global__ void __launch_bounds__(256)
topk_exact_pass1(const float* __restrict__ A, const float* __restrict__ D,
                 float* __restrict__ wdinv) {
  int lane = threadIdx.x & 63;
  int r = blockIdx.x * 4 + (threadIdx.x >> 6);
  size_t base = (size_t)r * N;
  int jm = wave_topk_exact(A + base, D + base, lane);
  float val = 0.0f;
  if (lane < KSEL) val = fmaxf(A[base + jm], 0.0f);
  float s = (lane < KSEL) ? val : 0.0f;
#pragma unroll
  for (int off = 32; off; off >>= 1) s += __shfl_xor(s, off);
  float dinv = (float)(1.0 / sqrt(1.0 + (double)s));
  if (lane == 0) wdinv[r] = dinv;
}

__global__ void __launch_bounds__(256)
fallback_pass2(const float* __restrict__ A, const float* __restrict__ D,
               const float* __restrict__ wdinv, float* __restrict__ out) {
  __shared__ float rows[4][N];
  int lane = threadIdx.x & 63;
  int w = threadIdx.x >> 6;
  int r = blockIdx.x * 4 + w;
  size_t base = (size_t)r * N;
  int i = r & (N - 1);
  int jm = wave_topk_exact(A + base, D + base, lane);
  float val = 0.0f;
  if (lane < KSEL) val = fmaxf(A[base + jm], 0.0f);
  float s = (lane < KSEL) ? val : 0.0f;
#pragma unroll
  for (int off = 32; off; off >>= 1) s += __shfl_xor(s, off);
  float di = (float)(1.0 / sqrt(1.0 + (double)s));
  float4* rv = reinterpret_cast<float4*>(rows[w]);
  float4 z = make_float4(0.f, 0.f, 0.f, 0.f);
#pragma unroll
  for (int q = 0; q < 8; ++q) rv[q * 64 + lane] = z;
  __syncthreads();
  if (lane < KSEL) {
    float dj = wdinv[(r & ~(N - 1)) + jm];
    atomicAdd(&rows[w][jm], di * val * dj);
  } else if (lane == KSEL) {
    atomicAdd(&rows[w][i], di * di);
  }
  __syncthreads();
  float4* o4 = reinterpret_cast<float4*>(out + base);
#pragma unroll
  for (int q = 0; q < 8; ++q) o4[q * 64 + lane] = rv[q * 64 + lane];
}

extern "C" void kernel_launch(void* const* d_in, const int* in_sizes, int n_in,
                              void* d_out, int out_size, void* d_ws, size_t ws_size,
                              hipStream_t stream) {
  const float* A = (const float*)d_in[0];
  const float* D = (const float*)d_in[1];
  float* out = (float*)d_out;
  char* ws = (char*)d_ws;
  size_t off_val  = 0;
  size_t off_idx  = off_val + (size_t)NR * KSEL * sizeof(float);
  size_t off_dinv = off_idx + (size_t)NR * KSEL * sizeof(int);
  size_t total    = off_dinv + (size_t)NR * sizeof(float);
  if (ws_size >= total) {
    float* wval  = (float*)(ws + off_val);
    int*   widx  = (int*)(ws + off_idx);
    float* wdinv = (float*)(ws + off_dinv);
    const int NP = SBROWS / 4;   // 2048 producer blocks per SB
    const int NS = SBROWS / 8;   // 1024 scatter blocks per SB
    // L0: produce SB0
    mixed<<<NP, 256, 0, stream>>>(A, D, wval, widx, wdinv, out, 0, NP, 0, 0);
    // L1..L3: produce SB(k) || scatter SB(k-1)
    for (int k = 1; k < 4; ++k)
      mixed<<<NP + NS, 256, 0, stream>>>(A, D, wval, widx, wdinv, out,
                                         k * SBROWS, NP, (k - 1) * SBROWS, NS);
    // L4: scatter SB3
    mixed<<<NS, 256, 0, stream>>>(A, D, wval, widx, wdinv, out, 0, 0, 3 * SBROWS, NS);
  } else {
    float* wdinv = (float*)ws;
    topk_exact_pass1<<<NR / 4, 256, 0, stream>>>(A, D, wdinv);
    fallback_pass2<<<NR / 4, 256, 0, stream>>>(A, D, wdinv, out);
  }
}

// Round 12
// 130.577 us; speedup vs baseline: 14.4542x; 1.3658x over previous
//
#include <hip/hip_runtime.h>

// _GSPostProcessor: out = D^{-1/2} (topk20(relu(A) + dope*1e-4)*relu(A) + I) D^{-1/2}
// B=16, N=2048, K=20.
// R12 = R7/R8 two-launch structure, with the scatter's stores switched from NT
// back to REGULAR float4 stores so the 256 MB output is absorbed by the 256 MiB
// L3 (write-back drains lazily, overlapping subsequent work — the overlap R9-R11
// failed to build explicitly). Pass1 keeps the R7-proven NT loads.
//  topk_fast  : wave-per-row, A-only NT read, set-exactness guard; rare rows redo
//               the exact R1-proven doped path inline.
//  scatter_v4 : 8 rows/block; thread t owns contiguous cols [8t,8t+8); composes
//               two float4 in registers (switch-indexed), 2 cached float4 stores.

static constexpr int N    = 2048;
static constexpr int KSEL = 20;
static constexpr int NR   = 16 * 2048;   // B*N rows

typedef unsigned int uint2v __attribute__((ext_vector_type(2)));
typedef float f32x4 __attribute__((ext_vector_type(4)));

#if __has_builtin(__builtin_nontemporal_load)
#define NT_LOAD(p) __builtin_nontemporal_load(p)
#else
#define NT_LOAD(p) (*(p))
#endif

// ---------------- cross-lane primitives ----------------
#if __has_builtin(__builtin_amdgcn_mov_dpp)
#define XD(v, ctrl) ((unsigned)__builtin_amdgcn_mov_dpp((int)(v), (ctrl), 0xF, 0xF, false))
#else
#define XD(v, ctrl) ((unsigned)__shfl_xor((int)(v), ((ctrl) == 0xB1 ? 1 : 2)))
#endif
#if __has_builtin(__builtin_amdgcn_ds_swizzle)
#define XS(v, imm) ((unsigned)__builtin_amdgcn_ds_swizzle((int)(v), (imm)))
#else
#define XS(v, imm) ((unsigned)__shfl_xor((int)(v), (((imm) >> 10) & 0x1F)))
#endif

__device__ __forceinline__ unsigned read_lane_u32(unsigned v, int srclane) {
#if __has_builtin(__builtin_amdgcn_readlane)
  return (unsigned)__builtin_amdgcn_readlane((int)v, srclane);
#else
  return (unsigned)__shfl((int)v, srclane, 64);
#endif
}

// compare-exchange: {A,B} = {self, partner} (order irrelevant); keep max iff km.
__device__ __forceinline__ void cex(unsigned& hi, unsigned& lo,
                                    unsigned Ahi, unsigned Alo,
                                    unsigned Bhi, unsigned Blo, bool km) {
  unsigned long long Av = ((unsigned long long)Ahi << 32) | Alo;
  unsigned long long Bv = ((unsigned long long)Bhi << 32) | Blo;
  bool sel = (km == (Av > Bv));
  hi = sel ? Ahi : Bhi;
  lo = sel ? Alo : Blo;
}

#define KM(K2, J) ((((lane & (J)) == 0)) != (((lane & (K2)) != 0)))
#define EX1(K2)  cex(hi, lo, hi, lo, XD(hi, 0xB1), XD(lo, 0xB1), KM(K2, 1))
#define EX2(K2)  cex(hi, lo, hi, lo, XD(hi, 0x4E), XD(lo, 0x4E), KM(K2, 2))
#define EX4(K2)  cex(hi, lo, hi, lo, XS(hi, 0x101F), XS(lo, 0x101F), KM(K2, 4))
#define EX8(K2)  cex(hi, lo, hi, lo, XS(hi, 0x201F), XS(lo, 0x201F), KM(K2, 8))
#if __has_builtin(__builtin_amdgcn_permlane16_swap)
#define EX16(K2) { uint2v r_ = __builtin_amdgcn_permlane16_swap(hi, hi, false, false); \
                   uint2v s_ = __builtin_amdgcn_permlane16_swap(lo, lo, false, false); \
                   cex(hi, lo, (unsigned)r_[0], (unsigned)s_[0], (unsigned)r_[1], (unsigned)s_[1], KM(K2, 16)); }
#else
#define EX16(K2) cex(hi, lo, hi, lo, (unsigned)__shfl_xor((int)hi, 16), (unsigned)__shfl_xor((int)lo, 16), KM(K2, 16))
#endif
#if __has_builtin(__builtin_amdgcn_permlane32_swap)
#define EX32(K2) { uint2v r_ = __builtin_amdgcn_permlane32_swap(hi, hi, false, false); \
                   uint2v s_ = __builtin_amdgcn_permlane32_swap(lo, lo, false, false); \
                   cex(hi, lo, (unsigned)r_[0], (unsigned)s_[0], (unsigned)r_[1], (unsigned)s_[1], KM(K2, 32)); }
#else
#define EX32(K2) cex(hi, lo, hi, lo, (unsigned)__shfl_xor((int)hi, 32), (unsigned)__shfl_xor((int)lo, 32), KM(K2, 32))
#endif

#define SORT64() do {                                     \
    EX1(2);                                               \
    EX2(4);  EX1(4);                                      \
    EX4(8);  EX2(8);  EX1(8);                             \
    EX8(16); EX4(16); EX2(16); EX1(16);                   \
    EX16(32); EX8(32); EX4(32); EX2(32); EX1(32);         \
    EX32(64); EX16(64); EX8(64); EX4(64); EX2(64); EX1(64); \
  } while (0)

// ---------------- exact (R1-proven) doped path ----------------
__device__ __forceinline__ void ins4(float vc, int jc,
                                     float& t0, float& t1, float& t2, float& t3,
                                     int& j0, int& j1, int& j2, int& j3) {
  bool b0 = vc > t0;
  float d0 = b0 ? t0 : vc; int e0 = b0 ? j0 : jc;
  t0 = b0 ? vc : t0;       j0 = b0 ? jc : j0;
  bool b1 = d0 > t1;
  float d1 = b1 ? t1 : d0; int e1 = b1 ? j1 : e0;
  t1 = b1 ? d0 : t1;       j1 = b1 ? e0 : j1;
  bool b2 = d1 > t2;
  float d2 = b2 ? t2 : d1; int e2 = b2 ? j2 : e1;
  t2 = b2 ? d1 : t2;       j2 = b2 ? e1 : j2;
  bool b3 = d2 > t3;
  t3 = b3 ? d2 : t3;       j3 = b3 ? e2 : j3;
}

__device__ __forceinline__ int wave_topk_exact(const float* __restrict__ Arow,
                                               const float* __restrict__ Drow,
                                               int lane) {
  float v[32];
  const float4* A4 = reinterpret_cast<const float4*>(Arow);
  const float4* D4 = reinterpret_cast<const float4*>(Drow);
#pragma unroll
  for (int c4 = 0; c4 < 8; ++c4) {
    float4 a = A4[c4 * 64 + lane];
    float4 d = D4[c4 * 64 + lane];
    v[c4 * 4 + 0] = __fadd_rn(fmaxf(a.x, 0.0f), __fmul_rn(d.x, 1e-4f));
    v[c4 * 4 + 1] = __fadd_rn(fmaxf(a.y, 0.0f), __fmul_rn(d.y, 1e-4f));
    v[c4 * 4 + 2] = __fadd_rn(fmaxf(a.z, 0.0f), __fmul_rn(d.z, 1e-4f));
    v[c4 * 4 + 3] = __fadd_rn(fmaxf(a.w, 0.0f), __fmul_rn(d.w, 1e-4f));
  }
  float t0 = -1.f, t1 = -1.f, t2 = -1.f, t3 = -1.f;
  int   j0 = 0,    j1 = 0,    j2 = 0,    j3 = 0;
#pragma unroll
  for (int c = 0; c < 32; ++c) {
    int jc = ((c >> 2) << 8) | (lane << 2) | (c & 3);
    ins4(v[c], jc, t0, t1, t2, t3, j0, j1, j2, j3);
  }
  unsigned consumed = 0;
  int jmine = 0;
#pragma unroll 1
  for (int it = 0; it < KSEL; ++it) {
    if (__any(t0 < 0.0f)) {
      if (t0 < 0.0f) {
        t0 = t1 = t2 = t3 = -1.f; j0 = j1 = j2 = j3 = 0;
#pragma unroll
        for (int c = 0; c < 32; ++c) {
          float vc = ((consumed >> c) & 1u) ? -1.0f : v[c];
          int jc = ((c >> 2) << 8) | (lane << 2) | (c & 3);
          ins4(vc, jc, t0, t1, t2, t3, j0, j1, j2, j3);
        }
      }
    }
    float m = t0;
#pragma unroll
    for (int off = 32; off; off >>= 1) m = fmaxf(m, __shfl_xor(m, off));
    int cj = (t0 == m) ? j0 : 0x7fffffff;
#pragma unroll
    for (int off = 32; off; off >>= 1) cj = min(cj, __shfl_xor(cj, off));
    if (lane == it) jmine = cj;
    if (((cj >> 2) & 63) == lane) {
      int c = ((cj >> 8) << 2) | (cj & 3);
      consumed |= (1u << c);
      t0 = t1; j0 = j1; t1 = t2; j1 = j2; t2 = t3; j2 = j3; t3 = -1.f; j3 = 0;
    }
  }
  return jmine;
}

// ---------------- pass 1: A-only fast path (NT loads) + inline exact redo ----------------
__global__ void __launch_bounds__(256)
topk_fast(const float* __restrict__ A, const float* __restrict__ D,
          float* __restrict__ wval, int* __restrict__ widx,
          float* __restrict__ wdinv) {
  __shared__ unsigned long long cand[4][64];
  __shared__ unsigned scnt[4];
  const float T = 2.05f;
  int lane = threadIdx.x & 63;
  int w = threadIdx.x >> 6;
  int r = blockIdx.x * 4 + w;
  size_t base = (size_t)r * N;
  const f32x4* A4 = reinterpret_cast<const f32x4*>(A + base);

  f32x4 a0 = NT_LOAD(A4 + lane);       f32x4 a1 = NT_LOAD(A4 + 64 + lane);
  f32x4 a2 = NT_LOAD(A4 + 128 + lane); f32x4 a3 = NT_LOAD(A4 + 192 + lane);
  f32x4 a4 = NT_LOAD(A4 + 256 + lane); f32x4 a5 = NT_LOAD(A4 + 320 + lane);
  f32x4 a6 = NT_LOAD(A4 + 384 + lane); f32x4 a7 = NT_LOAD(A4 + 448 + lane);

  cand[w][lane] = 0ull;        // padding sorts to the bottom (real keys > T > 0)
  if (lane == 0) scnt[w] = 0u;

#define PUSH1(AV, J) do {                                                      \
    float k_ = fmaxf((AV), 0.0f);                                              \
    if (k_ > T) {                                                              \
      unsigned p_ = atomicAdd(&scnt[w], 1u);                                   \
      if (p_ < 64u)                                                            \
        cand[w][p_] = ((unsigned long long)__float_as_uint(k_) << 32) |        \
                      (unsigned)(2047 - (J));                                  \
    }                                                                          \
  } while (0)
#define PUSH4(AA, C4) do {                                                     \
    int jb_ = ((C4) << 8) | (lane << 2);                                       \
    PUSH1(AA.x, jb_ + 0);                                                      \
    PUSH1(AA.y, jb_ + 1);                                                      \
    PUSH1(AA.z, jb_ + 2);                                                      \
    PUSH1(AA.w, jb_ + 3);                                                      \
  } while (0)

  PUSH4(a0, 0); PUSH4(a1, 1); PUSH4(a2, 2); PUSH4(a3, 3);
  PUSH4(a4, 4); PUSH4(a5, 5); PUSH4(a6, 6); PUSH4(a7, 7);
#undef PUSH4
#undef PUSH1

  // wave-private LDS; drain DS pipe before cross-lane reads
  __asm__ __volatile__("s_waitcnt lgkmcnt(0)" ::: "memory");
  unsigned cnt = scnt[w];
  unsigned long long kv = cand[w][lane];
  unsigned hi = (unsigned)(kv >> 32), lo = (unsigned)kv;
  SORT64();

  // Set-exactness guard: doped keys shift by at most +1e-4 (exact fp32 bound).
  float a19 = __uint_as_float(read_lane_u32(hi, 19));
  float a20 = __uint_as_float(read_lane_u32(hi, 20));
  bool decided = (a19 > __fadd_rn(a20, 1e-4f)) && (a19 > __fadd_rn(T, 1e-4f));
  bool bad = (cnt < (unsigned)KSEL) || (cnt > 64u) || !decided;  // wave-uniform

  int jsel = 2047 - (int)lo;
  float val = (lane < KSEL) ? __uint_as_float(hi) : 0.0f;  // sorted key IS relu(a)

  if (bad) {                    // ~0.3% of waves: exact doped redo
    int jm = wave_topk_exact(A + base, D + base, lane);
    jsel = jm;
    val = (lane < KSEL) ? fmaxf(A[base + jm], 0.0f) : 0.0f;
  }

  float s = val;
#pragma unroll
  for (int off = 32; off; off >>= 1) s += __shfl_xor(s, off);
  float dinv = (float)(1.0 / sqrt(1.0 + (double)s));       // row sum >= 1, never inf

  if (lane < KSEL) {
    wval[r * KSEL + lane] = val;
    widx[r * KSEL + lane] = jsel;
  }
  if (lane == 0) wdinv[r] = dinv;
}

// ---------------- pass 2: register-compose scatter, cached float4 stores ----------------
__global__ void __launch_bounds__(256)
scatter_v4(const float* __restrict__ wval, const int* __restrict__ widx,
           const float* __restrict__ wdinv, float* __restrict__ out) {
  int tid = threadIdx.x;
#pragma unroll 1
  for (int k = 0; k < 8; ++k) {
    int r = blockIdx.x * 8 + k;
    int i = r & (N - 1);
    int bb = r & ~(N - 1);               // batch row-base
    float di = wdinv[r];

    // thread owns contiguous cols [8*tid, 8*tid+8)
    float u0 = 0.f, u1 = 0.f, u2 = 0.f, u3 = 0.f,
          u4 = 0.f, u5 = 0.f, u6 = 0.f, u7 = 0.f;
    if ((i >> 3) == tid) {
      float dd = di * di;
      switch (i & 7) {
        case 0: u0 = dd; break; case 1: u1 = dd; break;
        case 2: u2 = dd; break; case 3: u3 = dd; break;
        case 4: u4 = dd; break; case 5: u5 = dd; break;
        case 6: u6 = dd; break; case 7: u7 = dd; break;
      }
    }
#pragma unroll
    for (int t = 0; t < KSEL; ++t) {
      int j = widx[r * KSEL + t];        // uniform -> scalar load
      if ((j >> 3) == tid) {             // <=20 of 256 threads hit
        float c = di * wval[r * KSEL + t] * wdinv[bb + j];
        switch (j & 7) {
          case 0: u0 += c; break; case 1: u1 += c; break;
          case 2: u2 += c; break; case 3: u3 += c; break;
          case 4: u4 += c; break; case 5: u5 += c; break;
          case 6: u6 += c; break; case 7: u7 += c; break;
        }
      }
    }
    // regular (cached) stores: land in L3, drain to HBM lazily
    float* o = out + (size_t)r * N + tid * 8;
    float4 p0 = make_float4(u0, u1, u2, u3);
    float4 p1 = make_float4(u4, u5, u6, u7);
    *reinterpret_cast<float4*>(o)     = p0;
    *reinterpret_cast<float4*>(o + 4) = p1;
  }
}

// ---------------- fallback (tiny ws): exact fused path, R1-proven ----------------
__global__ void __launch_bounds__(256)
topk_exact_pass1(const float* __restrict__ A, const float* __restrict__ D,
                 float* __restrict__ wdinv) {
  int lane = threadIdx.x & 63;
  int r = blockIdx.x * 4 + (threadIdx.x >> 6);
  size_t base = (size_t)r * N;
  int jm = wave_topk_exact(A + base, D + base, lane);
  float val = 0.0f;
  if (lane < KSEL) val = fmaxf(A[base + jm], 0.0f);
  float s = (lane < KSEL) ? val : 0.0f;
#pragma unroll
  for (int off = 32; off; off >>= 1) s += __shfl_xor(s, off);
  float dinv = (float)(1.0 / sqrt(1.0 + (double)s));
  if (lane == 0) wdinv[r] = dinv;
}

__global__ void __launch_bounds__(256)
fallback_pass2(const float* __restrict__ A, const float* __restrict__ D,
               const float* __restrict__ wdinv, float* __restrict__ out) {
  __shared__ float rows[4][N];
  int lane = threadIdx.x & 63;
  int w = threadIdx.x >> 6;
  int r = blockIdx.x * 4 + w;
  size_t base = (size_t)r * N;
  int i = r & (N - 1);
  int jm = wave_topk_exact(A + base, D + base, lane);
  float val = 0.0f;
  if (lane < KSEL) val = fmaxf(A[base + jm], 0.0f);
  float s = (lane < KSEL) ? val : 0.0f;
#pragma unroll
  for (int off = 32; off; off >>= 1) s += __shfl_xor(s, off);
  float di = (float)(1.0 / sqrt(1.0 + (double)s));
  float4* rv = reinterpret_cast<float4*>(rows[w]);
  float4 z = make_float4(0.f, 0.f, 0.f, 0.f);
#pragma unroll
  for (int q = 0; q < 8; ++q) rv[q * 64 + lane] = z;
  __syncthreads();
  if (lane < KSEL) {
    float dj = wdinv[(r & ~(N - 1)) + jm];
    atomicAdd(&rows[w][jm], di * val * dj);
  } else if (lane == KSEL) {
    atomicAdd(&rows[w][i], di * di);
  }
  __syncthreads();
  float4* o4 = reinterpret_cast<float4*>(out + base);
#pragma unroll
  for (int q = 0; q < 8; ++q) o4[q * 64 + lane] = rv[q * 64 + lane];
}

extern "C" void kernel_launch(void* const* d_in, const int* in_sizes, int n_in,
                              void* d_out, int out_size, void* d_ws, size_t ws_size,
                              hipStream_t stream) {
  const float* A = (const float*)d_in[0];
  const float* D = (const float*)d_in[1];
  float* out = (float*)d_out;
  char* ws = (char*)d_ws;
  size_t off_val  = 0;
  size_t off_idx  = off_val + (size_t)NR * KSEL * sizeof(float);
  size_t off_dinv = off_idx + (size_t)NR * KSEL * sizeof(int);
  size_t total    = off_dinv + (size_t)NR * sizeof(float);
  if (ws_size >= total) {
    float* wval  = (float*)(ws + off_val);
    int*   widx  = (int*)(ws + off_idx);
    float* wdinv = (float*)(ws + off_dinv);
    topk_fast<<<NR / 4, 256, 0, stream>>>(A, D, wval, widx, wdinv);
    scatter_v4<<<NR / 8, 256, 0, stream>>>(wval, widx, wdinv, out);
  } else {
    float* wdinv = (float*)ws;
    topk_exact_pass1<<<NR / 4, 256, 0, stream>>>(A, D, wdinv);
    fallback_pass2<<<NR / 4, 256, 0, stream>>>(A, D, wdinv, out);
  }
}

// Round 13
// 126.767 us; speedup vs baseline: 14.8886x; 1.0301x over previous
//
#include <hip/hip_runtime.h>

// _GSPostProcessor: out = D^{-1/2} (topk20(relu(A) + dope*1e-4)*relu(A) + I) D^{-1/2}
// B=16, N=2048, K=20.
// FINAL (= R7, best measured: 126.9 us, absmax 0.0):
//  - pass1 A-row loads nontemporal (A read exactly once; bypasses the L1-allocate
//    path that caps cached streaming reads at ~3.3 TB/s effective)
//  - scatter output stores nontemporal (out never re-read)
//  topk_fast  : wave-per-row, A-only read, set-exactness guard (doped top-20 set
//               certified from undoped sort when gap > 1e-4); uncertain rows
//               (~0.3%) redo the exact R1-proven doped path inline.
//  scatter_reg: block-per-row register compose, 8 coalesced NT stores per thread.
// Empirical roofline: 256 MB read @ ~3.2 TB/s (six structural variants all cap
// here) + 256 MB write @ ~7 TB/s + ~5 us overhead ~= 123 us; this kernel: ~127.

static constexpr int N    = 2048;
static constexpr int KSEL = 20;
static constexpr int NR   = 16 * 2048;   // B*N rows

typedef unsigned int uint2v __attribute__((ext_vector_type(2)));
typedef float f32x4 __attribute__((ext_vector_type(4)));

#if __has_builtin(__builtin_nontemporal_load)
#define NT_LOAD(p) __builtin_nontemporal_load(p)
#else
#define NT_LOAD(p) (*(p))
#endif
#if __has_builtin(__builtin_nontemporal_store)
#define NT_STORE(v, p) __builtin_nontemporal_store((v), (p))
#else
#define NT_STORE(v, p) (*(p) = (v))
#endif

// ---------------- cross-lane primitives ----------------
#if __has_builtin(__builtin_amdgcn_mov_dpp)
#define XD(v, ctrl) ((unsigned)__builtin_amdgcn_mov_dpp((int)(v), (ctrl), 0xF, 0xF, false))
#else
#define XD(v, ctrl) ((unsigned)__shfl_xor((int)(v), ((ctrl) == 0xB1 ? 1 : 2)))
#endif
#if __has_builtin(__builtin_amdgcn_ds_swizzle)
#define XS(v, imm) ((unsigned)__builtin_amdgcn_ds_swizzle((int)(v), (imm)))
#else
#define XS(v, imm) ((unsigned)__shfl_xor((int)(v), (((imm) >> 10) & 0x1F)))
#endif

__device__ __forceinline__ unsigned read_lane_u32(unsigned v, int srclane) {
#if __has_builtin(__builtin_amdgcn_readlane)
  return (unsigned)__builtin_amdgcn_readlane((int)v, srclane);
#else
  return (unsigned)__shfl((int)v, srclane, 64);
#endif
}

// compare-exchange: {A,B} = {self, partner} (order irrelevant); keep max iff km.
__device__ __forceinline__ void cex(unsigned& hi, unsigned& lo,
                                    unsigned Ahi, unsigned Alo,
                                    unsigned Bhi, unsigned Blo, bool km) {
  unsigned long long Av = ((unsigned long long)Ahi << 32) | Alo;
  unsigned long long Bv = ((unsigned long long)Bhi << 32) | Blo;
  bool sel = (km == (Av > Bv));
  hi = sel ? Ahi : Bhi;
  lo = sel ? Alo : Blo;
}

#define KM(K2, J) ((((lane & (J)) == 0)) != (((lane & (K2)) != 0)))
#define EX1(K2)  cex(hi, lo, hi, lo, XD(hi, 0xB1), XD(lo, 0xB1), KM(K2, 1))
#define EX2(K2)  cex(hi, lo, hi, lo, XD(hi, 0x4E), XD(lo, 0x4E), KM(K2, 2))
#define EX4(K2)  cex(hi, lo, hi, lo, XS(hi, 0x101F), XS(lo, 0x101F), KM(K2, 4))
#define EX8(K2)  cex(hi, lo, hi, lo, XS(hi, 0x201F), XS(lo, 0x201F), KM(K2, 8))
#if __has_builtin(__builtin_amdgcn_permlane16_swap)
#define EX16(K2) { uint2v r_ = __builtin_amdgcn_permlane16_swap(hi, hi, false, false); \
                   uint2v s_ = __builtin_amdgcn_permlane16_swap(lo, lo, false, false); \
                   cex(hi, lo, (unsigned)r_[0], (unsigned)s_[0], (unsigned)r_[1], (unsigned)s_[1], KM(K2, 16)); }
#else
#define EX16(K2) cex(hi, lo, hi, lo, (unsigned)__shfl_xor((int)hi, 16), (unsigned)__shfl_xor((int)lo, 16), KM(K2, 16))
#endif
#if __has_builtin(__builtin_amdgcn_permlane32_swap)
#define EX32(K2) { uint2v r_ = __builtin_amdgcn_permlane32_swap(hi, hi, false, false); \
                   uint2v s_ = __builtin_amdgcn_permlane32_swap(lo, lo, false, false); \
                   cex(hi, lo, (unsigned)r_[0], (unsigned)s_[0], (unsigned)r_[1], (unsigned)s_[1], KM(K2, 32)); }
#else
#define EX32(K2) cex(hi, lo, hi, lo, (unsigned)__shfl_xor((int)hi, 32), (unsigned)__shfl_xor((int)lo, 32), KM(K2, 32))
#endif

// ---------------- exact (R1-proven) doped path ----------------
__device__ __forceinline__ void ins4(float vc, int jc,
                                     float& t0, float& t1, float& t2, float& t3,
                                     int& j0, int& j1, int& j2, int& j3) {
  bool b0 = vc > t0;
  float d0 = b0 ? t0 : vc; int e0 = b0 ? j0 : jc;
  t0 = b0 ? vc : t0;       j0 = b0 ? jc : j0;
  bool b1 = d0 > t1;
  float d1 = b1 ? t1 : d0; int e1 = b1 ? j1 : e0;
  t1 = b1 ? d0 : t1;       j1 = b1 ? e0 : j1;
  bool b2 = d1 > t2;
  float d2 = b2 ? t2 : d1; int e2 = b2 ? j2 : e1;
  t2 = b2 ? d1 : t2;       j2 = b2 ? e1 : j2;
  bool b3 = d2 > t3;
  t3 = b3 ? d2 : t3;       j3 = b3 ? e2 : j3;
}

__device__ __forceinline__ int wave_topk_exact(const float* __restrict__ Arow,
                                               const float* __restrict__ Drow,
                                               int lane) {
  float v[32];
  const float4* A4 = reinterpret_cast<const float4*>(Arow);
  const float4* D4 = reinterpret_cast<const float4*>(Drow);
#pragma unroll
  for (int c4 = 0; c4 < 8; ++c4) {
    float4 a = A4[c4 * 64 + lane];
    float4 d = D4[c4 * 64 + lane];
    v[c4 * 4 + 0] = __fadd_rn(fmaxf(a.x, 0.0f), __fmul_rn(d.x, 1e-4f));
    v[c4 * 4 + 1] = __fadd_rn(fmaxf(a.y, 0.0f), __fmul_rn(d.y, 1e-4f));
    v[c4 * 4 + 2] = __fadd_rn(fmaxf(a.z, 0.0f), __fmul_rn(d.z, 1e-4f));
    v[c4 * 4 + 3] = __fadd_rn(fmaxf(a.w, 0.0f), __fmul_rn(d.w, 1e-4f));
  }
  float t0 = -1.f, t1 = -1.f, t2 = -1.f, t3 = -1.f;
  int   j0 = 0,    j1 = 0,    j2 = 0,    j3 = 0;
#pragma unroll
  for (int c = 0; c < 32; ++c) {
    int jc = ((c >> 2) << 8) | (lane << 2) | (c & 3);
    ins4(v[c], jc, t0, t1, t2, t3, j0, j1, j2, j3);
  }
  unsigned consumed = 0;
  int jmine = 0;
#pragma unroll 1
  for (int it = 0; it < KSEL; ++it) {
    if (__any(t0 < 0.0f)) {
      if (t0 < 0.0f) {
        t0 = t1 = t2 = t3 = -1.f; j0 = j1 = j2 = j3 = 0;
#pragma unroll
        for (int c = 0; c < 32; ++c) {
          float vc = ((consumed >> c) & 1u) ? -1.0f : v[c];
          int jc = ((c >> 2) << 8) | (lane << 2) | (c & 3);
          ins4(vc, jc, t0, t1, t2, t3, j0, j1, j2, j3);
        }
      }
    }
    float m = t0;
#pragma unroll
    for (int off = 32; off; off >>= 1) m = fmaxf(m, __shfl_xor(m, off));
    int cj = (t0 == m) ? j0 : 0x7fffffff;
#pragma unroll
    for (int off = 32; off; off >>= 1) cj = min(cj, __shfl_xor(cj, off));
    if (lane == it) jmine = cj;
    if (((cj >> 2) & 63) == lane) {
      int c = ((cj >> 8) << 2) | (cj & 3);
      consumed |= (1u << c);
      t0 = t1; j0 = j1; t1 = t2; j1 = j2; t2 = t3; j2 = j3; t3 = -1.f; j3 = 0;
    }
  }
  return jmine;
}

// ---------------- pass 1: A-only fast path (nt loads) + inline exact redo ----------------
__global__ void __launch_bounds__(256)
topk_fast(const float* __restrict__ A, const float* __restrict__ D,
          float* __restrict__ wval, int* __restrict__ widx,
          float* __restrict__ wdinv) {
  __shared__ unsigned long long cand[4][64];
  __shared__ unsigned scnt[4];
  const float T = 2.05f;
  int lane = threadIdx.x & 63;
  int w = threadIdx.x >> 6;
  int r = blockIdx.x * 4 + w;
  size_t base = (size_t)r * N;
  const f32x4* A4 = reinterpret_cast<const f32x4*>(A + base);

  f32x4 a0 = NT_LOAD(A4 + lane);       f32x4 a1 = NT_LOAD(A4 + 64 + lane);
  f32x4 a2 = NT_LOAD(A4 + 128 + lane); f32x4 a3 = NT_LOAD(A4 + 192 + lane);
  f32x4 a4 = NT_LOAD(A4 + 256 + lane); f32x4 a5 = NT_LOAD(A4 + 320 + lane);
  f32x4 a6 = NT_LOAD(A4 + 384 + lane); f32x4 a7 = NT_LOAD(A4 + 448 + lane);

  cand[w][lane] = 0ull;        // padding sorts to the bottom (real keys > T > 0)
  if (lane == 0) scnt[w] = 0u;

#define PUSH1(AV, J) do {                                                      \
    float k_ = fmaxf((AV), 0.0f);                                              \
    if (k_ > T) {                                                              \
      unsigned p_ = atomicAdd(&scnt[w], 1u);                                   \
      if (p_ < 64u)                                                            \
        cand[w][p_] = ((unsigned long long)__float_as_uint(k_) << 32) |        \
                      (unsigned)(2047 - (J));                                  \
    }                                                                          \
  } while (0)
#define PUSH4(AA, C4) do {                                                     \
    int jb_ = ((C4) << 8) | (lane << 2);                                       \
    PUSH1(AA.x, jb_ + 0);                                                      \
    PUSH1(AA.y, jb_ + 1);                                                      \
    PUSH1(AA.z, jb_ + 2);                                                      \
    PUSH1(AA.w, jb_ + 3);                                                      \
  } while (0)

  PUSH4(a0, 0); PUSH4(a1, 1); PUSH4(a2, 2); PUSH4(a3, 3);
  PUSH4(a4, 4); PUSH4(a5, 5); PUSH4(a6, 6); PUSH4(a7, 7);
#undef PUSH4
#undef PUSH1

  // wave-private LDS; drain DS pipe before cross-lane reads
  __asm__ __volatile__("s_waitcnt lgkmcnt(0)" ::: "memory");
  unsigned cnt = scnt[w];
  unsigned long long kv = cand[w][lane];
  unsigned hi = (unsigned)(kv >> 32), lo = (unsigned)kv;

  // 64-lane bitonic sort, descending by (a'bits, 2047-j)
  EX1(2);
  EX2(4);  EX1(4);
  EX4(8);  EX2(8);  EX1(8);
  EX8(16); EX4(16); EX2(16); EX1(16);
  EX16(32); EX8(32); EX4(32); EX2(32); EX1(32);
  EX32(64); EX16(64); EX8(64); EX4(64); EX2(64); EX1(64);

  // Set-exactness guard: doped keys shift by at most +1e-4 (exact fp32 bound).
  float a19 = __uint_as_float(read_lane_u32(hi, 19));
  float a20 = __uint_as_float(read_lane_u32(hi, 20));
  bool decided = (a19 > __fadd_rn(a20, 1e-4f)) && (a19 > __fadd_rn(T, 1e-4f));
  bool bad = (cnt < (unsigned)KSEL) || (cnt > 64u) || !decided;  // wave-uniform

  int jsel = 2047 - (int)lo;
  float val = (lane < KSEL) ? __uint_as_float(hi) : 0.0f;  // sorted key IS relu(a)

  if (bad) {                    // ~0.3% of waves: exact doped redo (reads this row's dope)
    int jm = wave_topk_exact(A + base, D + base, lane);
    jsel = jm;
    val = (lane < KSEL) ? fmaxf(A[base + jm], 0.0f) : 0.0f;
  }

  float s = val;
#pragma unroll
  for (int off = 32; off; off >>= 1) s += __shfl_xor(s, off);
  float dinv = (float)(1.0 / sqrt(1.0 + (double)s));       // row sum >= 1, never inf

  if (lane < KSEL) {
    wval[r * KSEL + lane] = val;
    widx[r * KSEL + lane] = jsel;
  }
  if (lane == 0) wdinv[r] = dinv;
}

// ---------------- pass 2: register-compose scatter (nt stores) ----------------
__global__ void __launch_bounds__(256)
scatter_reg(const float* __restrict__ wval, const int* __restrict__ widx,
            const float* __restrict__ wdinv, float* __restrict__ out) {
  int r = blockIdx.x;
  int tid = threadIdx.x;
  int i = r & (N - 1);
  int bb = r & ~(N - 1);                 // batch row-base
  float di = wdinv[r];

  float v0 = 0.f, v1 = 0.f, v2 = 0.f, v3 = 0.f,
        v4 = 0.f, v5 = 0.f, v6 = 0.f, v7 = 0.f;
  // diagonal term first (same additive composition as the proven LDS scatter;
  // 2-term fp32 add is order-invariant bitwise)
  if ((i & 255) == tid) {
    float dd = di * di;
    switch (i >> 8) {
      case 0: v0 = dd; break; case 1: v1 = dd; break;
      case 2: v2 = dd; break; case 3: v3 = dd; break;
      case 4: v4 = dd; break; case 5: v5 = dd; break;
      case 6: v6 = dd; break; case 7: v7 = dd; break;
    }
  }
#pragma unroll
  for (int t = 0; t < KSEL; ++t) {
    int j = widx[r * KSEL + t];          // uniform -> scalar load
    if ((j & 255) == tid) {              // <=20 of 256 threads hit
      float c = di * wval[r * KSEL + t] * wdinv[bb + j];
      switch (j >> 8) {
        case 0: v0 += c; break; case 1: v1 += c; break;
        case 2: v2 += c; break; case 3: v3 += c; break;
        case 4: v4 += c; break; case 5: v5 += c; break;
        case 6: v6 += c; break; case 7: v7 += c; break;
      }
    }
  }
  float* o = out + (size_t)r * N;
  NT_STORE(v0, o + tid);         NT_STORE(v1, o + 256 + tid);
  NT_STORE(v2, o + 512 + tid);   NT_STORE(v3, o + 768 + tid);
  NT_STORE(v4, o + 1024 + tid);  NT_STORE(v5, o + 1280 + tid);
  NT_STORE(v6, o + 1536 + tid);  NT_STORE(v7, o + 1792 + tid);
}

// ---------------- fallback (tiny ws): exact fused path, R1-proven ----------------
__global__ void __launch_bounds__(256)
topk_exact_pass1(const float* __restrict__ A, const float* __restrict__ D,
                 float* __restrict__ wdinv) {
  int lane = threadIdx.x & 63;
  int r = blockIdx.x * 4 + (threadIdx.x >> 6);
  size_t base = (size_t)r * N;
  int jm = wave_topk_exact(A + base, D + base, lane);
  float val = 0.0f;
  if (lane < KSEL) val = fmaxf(A[base + jm], 0.0f);
  float s = (lane < KSEL) ? val : 0.0f;
#pragma unroll
  for (int off = 32; off; off >>= 1) s += __shfl_xor(s, off);
  float dinv = (float)(1.0 / sqrt(1.0 + (double)s));
  if (lane == 0) wdinv[r] = dinv;
}

__global__ void __launch_bounds__(256)
fallback_pass2(const float* __restrict__ A, const float* __restrict__ D,
               const float* __restrict__ wdinv, float* __restrict__ out) {
  __shared__ float rows[4][N];
  int lane = threadIdx.x & 63;
  int w = threadIdx.x >> 6;
  int r = blockIdx.x * 4 + w;
  size_t base = (size_t)r * N;
  int i = r & (N - 1);
  int jm = wave_topk_exact(A + base, D + base, lane);
  float val = 0.0f;
  if (lane < KSEL) val = fmaxf(A[base + jm], 0.0f);
  float s = (lane < KSEL) ? val : 0.0f;
#pragma unroll
  for (int off = 32; off; off >>= 1) s += __shfl_xor(s, off);
  float di = (float)(1.0 / sqrt(1.0 + (double)s));
  float4* rv = reinterpret_cast<float4*>(rows[w]);
  float4 z = make_float4(0.f, 0.f, 0.f, 0.f);
#pragma unroll
  for (int q = 0; q < 8; ++q) rv[q * 64 + lane] = z;
  __syncthreads();
  if (lane < KSEL) {
    float dj = wdinv[(r & ~(N - 1)) + jm];
    atomicAdd(&rows[w][jm], di * val * dj);
  } else if (lane == KSEL) {
    atomicAdd(&rows[w][i], di * di);
  }
  __syncthreads();
  float4* o4 = reinterpret_cast<float4*>(out + base);
#pragma unroll
  for (int q = 0; q < 8; ++q) o4[q * 64 + lane] = rv[q * 64 + lane];
}

extern "C" void kernel_launch(void* const* d_in, const int* in_sizes, int n_in,
                              void* d_out, int out_size, void* d_ws, size_t ws_size,
                              hipStream_t stream) {
  const float* A = (const float*)d_in[0];
  const float* D = (const float*)d_in[1];
  float* out = (float*)d_out;
  char* ws = (char*)d_ws;
  size_t off_val  = 0;
  size_t off_idx  = off_val + (size_t)NR * KSEL * sizeof(float);
  size_t off_dinv = off_idx + (size_t)NR * KSEL * sizeof(int);
  size_t total    = off_dinv + (size_t)NR * sizeof(float);
  if (ws_size >= total) {
    float* wval  = (float*)(ws + off_val);
    int*   widx  = (int*)(ws + off_idx);
    float* wdinv = (float*)(ws + off_dinv);
    topk_fast<<<NR / 4, 256, 0, stream>>>(A, D, wval, widx, wdinv);
    scatter_reg<<<NR, 256, 0, stream>>>(wval, widx, wdinv, out);
  } else {
    float* wdinv = (float*)ws;
    topk_exact_pass1<<<NR / 4, 256, 0, stream>>>(A, D, wdinv);
    fallback_pass2<<<NR / 4, 256, 0, stream>>>(A, D, wdinv, out);
  }
}